// Round 1
// baseline (369.849 us; speedup 1.0000x reference)
//
#include <hip/hip_runtime.h>

#define NB 8
#define CC 3
#define HH 720
#define WW 1280
#define EPSL 1e-6f
#define HSEG 24            // 720 = 30*24
#define NSEG (HH / HSEG)   // 30
#define OUTC 56            // output cols per wave (64 lanes - 8 halo)
#define NSTRIP 23          // 23*56 = 1288 >= 1280
#define NITER (HSEG + 8)   // 32  (main loop = 24 = 3*8, clean unroll-8)
#define NUNIT (NSTRIP * NSEG * NB)  // 5520 waves
#define NBLK (NUNIT / 4)            // 1380 blocks

__device__ __forceinline__ float bperm(int addr, float x) {
    return __int_as_float(__builtin_amdgcn_ds_bpermute(addr, __float_as_int(x)));
}

__global__ __launch_bounds__(256, 5)
void fused_loss_kernel(const float* __restrict__ left,
                       const float* __restrict__ right,
                       const float* __restrict__ disp,
                       float* __restrict__ out)
{
    const int t    = threadIdx.x;
    const int lane = t & 63;
    const int u    = blockIdx.x * 4 + (t >> 6);
    const int strip = u % NSTRIP;
    const int hseg  = (u / NSTRIP) % NSEG;
    const int n     = u / (NSTRIP * NSEG);
    const int h0 = hseg * HSEG;
    const int gc  = strip * OUTC + lane - 4;          // column this lane owns
    const int gcc = min(max(gc, 0), WW - 1);          // clamped (safe addresses)
    const bool out_lane = (lane >= 4) && (lane < 4 + OUTC) && (gc < WW);
    const size_t plane = (size_t)HH * WW;
    const float* __restrict__ dispn  = disp  + (size_t)n * plane;
    const float* __restrict__ leftn  = left  + (size_t)n * CC * plane;
    const float* __restrict__ rightn = right + (size_t)n * CC * plane;

    // hoisted bpermute byte-addresses for the symmetric 3x3 window tree
    const int a_m1 = ((lane + 63) & 63) << 2;
    const int a_p1 = ((lane +  1) & 63) << 2;
    const int a_m3 = ((lane + 61) & 63) << 2;
    const int a_p3 = ((lane +  3) & 63) << 2;

    // vertical rolling ring (h-boxed rows, delay 8) — registers
    float4 rg1 = make_float4(0.f,0.f,0.f,0.f);
    float4 rg2=rg1, rg3=rg1, rg4=rg1, rg5=rg1, rg6=rg1, rg7=rg1, rg8=rg1;
    // center-row pixel chain (delay 4): left c0..c2, warped-right c0..c2
    float p1l0=0,p1l1=0,p1l2=0,p1r0=0,p1r1=0,p1r2=0;
    float p2l0=0,p2l1=0,p2l2=0,p2r0=0,p2r1=0,p2r2=0;
    float p3l0=0,p3l1=0,p3l2=0,p3r0=0,p3r1=0,p3r2=0;
    float p4l0=0,p4l1=0,p4l2=0,p4r0=0,p4r1=0,p4r2=0;

    const int r0 = h0 - 4;

    // ---- prologue: rows r0 and r0+1 ----
    int rcl = min(max(r0, 0), HH - 1);
    size_t ro = (size_t)rcl * WW + gcc;
    float dA  = dispn[ro];
    float al0 = leftn[ro], al1 = leftn[plane + ro], al2 = leftn[2*plane + ro];
    rcl = min(max(r0 + 1, 0), HH - 1);
    ro  = (size_t)rcl * WW + gcc;
    float dB  = dispn[ro];
    float bl0 = leftn[ro], bl1 = leftn[plane + ro], bl2 = leftn[2*plane + ro];
    (void)dA;

    float aw0, aw1, ag00, ag01, ag10, ag11, ag20, ag21;
    {
        float ix  = (float)gc - dA;
        float x0f = floorf(ix), wx = ix - x0f;
        int x0i = (int)x0f, x1i = x0i + 1;
        float v0 = (x0i >= 0 && x0i < WW) ? 1.f : 0.f;
        float v1 = (x1i >= 0 && x1i < WW) ? 1.f : 0.f;
        int i0 = min(max(x0i, 0), WW - 1), i1 = min(max(x1i, 0), WW - 1);
        aw0 = v0 * (1.f - wx); aw1 = v1 * wx;
        size_t rb = (size_t)min(max(r0, 0), HH - 1) * WW;
        ag00 = rightn[rb + i0];           ag01 = rightn[rb + i1];
        ag10 = rightn[plane + rb + i0];   ag11 = rightn[plane + rb + i1];
        ag20 = rightn[2*plane + rb + i0]; ag21 = rightn[2*plane + rb + i1];
    }

    float4 vsum = make_float4(0.f,0.f,0.f,0.f);
    float acc = 0.f;

    auto body = [&](int iter, bool do_out) {
        const int r = r0 + iter;

        // (1) issue loads for row r+2 (consumed next iter)
        int rcl2 = min(max(r + 2, 0), HH - 1);
        size_t ro2 = (size_t)rcl2 * WW + gcc;
        float dC  = dispn[ro2];
        float cl0 = leftn[ro2], cl1 = leftn[plane + ro2], cl2 = leftn[2*plane + ro2];

        // (2) issue gathers for row r+1 using dB (loaded last iter)
        float bw0, bw1, bg00, bg01, bg10, bg11, bg20, bg21;
        {
            float ix  = (float)gc - dB;
            float x0f = floorf(ix), wx = ix - x0f;
            int x0i = (int)x0f, x1i = x0i + 1;
            float v0 = (x0i >= 0 && x0i < WW) ? 1.f : 0.f;
            float v1 = (x1i >= 0 && x1i < WW) ? 1.f : 0.f;
            int i0 = min(max(x0i, 0), WW - 1), i1 = min(max(x1i, 0), WW - 1);
            bw0 = v0 * (1.f - wx); bw1 = v1 * wx;
            size_t rb = (size_t)min(max(r + 1, 0), HH - 1) * WW;
            bg00 = rightn[rb + i0];           bg01 = rightn[rb + i1];
            bg10 = rightn[plane + rb + i0];   bg11 = rightn[plane + rb + i1];
            bg20 = rightn[2*plane + rb + i0]; bg21 = rightn[2*plane + rb + i1];
        }

        // (3) combine raw channel sums for row r (gathers issued last iter)
        float rca = ag00*aw0 + ag01*aw1;
        float rcb = ag10*aw0 + ag11*aw1;
        float rcc = ag20*aw0 + ag21*aw1;
        bool valr = (r >= 0) && (r < HH) && (gc >= 0) && (gc < WW);
        float rx = al0 + al1 + al2;
        float ry = al0*al0 + al1*al1 + al2*al2;
        float rz = rca + rcb + rcc;
        float rw = rca*rca + rcb*rcb + rcc*rcc;
        rx = valr ? rx : 0.f;  ry = valr ? ry : 0.f;
        rz = valr ? rz : 0.f;  rw = valr ? rw : 0.f;

        // (4) horizontal 9-sum via symmetric 3x3 tree: 4 bpermutes/var, depth 2
        float sx = bperm(a_m1, rx) + rx + bperm(a_p1, rx);
        float sy = bperm(a_m1, ry) + ry + bperm(a_p1, ry);
        float sz = bperm(a_m1, rz) + rz + bperm(a_p1, rz);
        float sw = bperm(a_m1, rw) + rw + bperm(a_p1, rw);
        float hx = bperm(a_m3, sx) + sx + bperm(a_p3, sx);
        float hy = bperm(a_m3, sy) + sy + bperm(a_p3, sy);
        float hz = bperm(a_m3, sz) + sz + bperm(a_p3, sz);
        float hw = bperm(a_m3, sw) + sw + bperm(a_p3, sw);

        // (5) vertical rolling add
        vsum.x += hx; vsum.y += hy; vsum.z += hz; vsum.w += hw;

        // (6) output row h = r-4
        if (do_out) {
            float ml   = vsum.x * (1.f / 81.f);
            float msl  = vsum.y * (1.f / 81.f);
            float stdl = (msl - ml * ml) * (81.f / 80.f);
            float invl = __builtin_amdgcn_rcpf(stdl + EPSL);
            float mr   = vsum.z * (1.f / 81.f);
            float msr  = vsum.w * (1.f / 81.f);
            float stdr = (msr - mr * mr) * (81.f / 80.f);
            float invr = __builtin_amdgcn_rcpf(stdr + EPSL);
            if (out_lane) {
                float av, bv;
                av = (p4l0 - ml) * invl; bv = (p4r0 - mr) * invr;
                acc += fabsf((av - bv) * stdl);
                av = (p4l1 - ml) * invl; bv = (p4r1 - mr) * invr;
                acc += fabsf((av - bv) * stdl);
                av = (p4l2 - ml) * invl; bv = (p4r2 - mr) * invr;
                acc += fabsf((av - bv) * stdl);
            }
            // (7) subtract h-boxed row pushed 8 iters ago
            vsum.x -= rg8.x; vsum.y -= rg8.y; vsum.z -= rg8.z; vsum.w -= rg8.w;
        }

        // (8) shift rings (renamed away by unroll)
        rg8 = rg7; rg7 = rg6; rg6 = rg5; rg5 = rg4; rg4 = rg3; rg3 = rg2; rg2 = rg1;
        rg1 = make_float4(hx, hy, hz, hw);
        p4l0=p3l0; p4l1=p3l1; p4l2=p3l2; p4r0=p3r0; p4r1=p3r1; p4r2=p3r2;
        p3l0=p2l0; p3l1=p2l1; p3l2=p2l2; p3r0=p2r0; p3r1=p2r1; p3r2=p2r2;
        p2l0=p1l0; p2l1=p1l1; p2l2=p1l2; p2r0=p1r0; p2r1=p1r1; p2r2=p1r2;
        p1l0=al0;  p1l1=al1;  p1l2=al2;  p1r0=rca;  p1r1=rcb;  p1r2=rcc;

        // (9) rotate packets: B -> A (row r+1 becomes current), C -> B
        al0=bl0; al1=bl1; al2=bl2;
        aw0=bw0; aw1=bw1;
        ag00=bg00; ag01=bg01; ag10=bg10; ag11=bg11; ag20=bg20; ag21=bg21;
        dB=dC; bl0=cl0; bl1=cl1; bl2=cl2;
    };

    // warm-up rows: no output, fully unrolled (ring shifts renamed)
#pragma unroll
    for (int it = 0; it < 8; ++it) body(it, false);
    // main rows: always output; unroll 8 == ring depth so shifts rename away
#pragma unroll 8
    for (int it = 8; it < NITER; ++it) body(it, true);

    // ---- reduction: wave shuffle -> LDS (4 slots) -> atomic ----
#pragma unroll
    for (int off = 32; off > 0; off >>= 1)
        acc += __shfl_down(acc, off, 64);
    __shared__ float red[4];
    if (lane == 0) red[t >> 6] = acc;
    __syncthreads();
    if (t == 0) {
        float s = red[0] + red[1] + red[2] + red[3];
        const float inv_count = 1.f / ((float)NB * CC * HH * WW);
        atomicAdd(out, s * inv_count);
    }
}

extern "C" void kernel_launch(void* const* d_in, const int* in_sizes, int n_in,
                              void* d_out, int out_size, void* d_ws, size_t ws_size,
                              hipStream_t stream) {
    const float* left  = (const float*)d_in[0];
    const float* right = (const float*)d_in[1];
    const float* disp  = (const float*)d_in[2];
    float* out = (float*)d_out;

    hipMemsetAsync(out, 0, sizeof(float) * out_size, stream);

    hipLaunchKernelGGL(fused_loss_kernel, dim3(NBLK), dim3(256), 0, stream,
                       left, right, disp, out);
}

// Round 2
// 241.400 us; speedup vs baseline: 1.5321x; 1.5321x over previous
//
#include <hip/hip_runtime.h>

#define NB 8
#define CC 3
#define HH 720
#define WW 1280
#define EPSL 1e-6f
#define HSEG 30            // 720 = 24*30
#define NSEG (HH / HSEG)   // 24
#define OUTC 56            // output cols per wave (64 lanes - 8 halo)
#define NSTRIP 23          // 23*56 = 1288 >= 1280
#define NITER (HSEG + 8)   // 38
#define NUNIT (NSTRIP * NSEG * NB)  // 4416 waves
#define NBLK (NUNIT / 4)            // 1104 blocks

__device__ __forceinline__ float bperm(int addr, float x) {
    return __int_as_float(__builtin_amdgcn_ds_bpermute(addr, __float_as_int(x)));
}

__global__ __launch_bounds__(256)
void fused_loss_kernel(const float* __restrict__ left,
                       const float* __restrict__ right,
                       const float* __restrict__ disp,
                       float* __restrict__ out)
{
    const int t    = threadIdx.x;
    const int lane = t & 63;
    const int u    = blockIdx.x * 4 + (t >> 6);
    const int strip = u % NSTRIP;
    const int hseg  = (u / NSTRIP) % NSEG;
    const int n     = u / (NSTRIP * NSEG);
    const int h0 = hseg * HSEG;
    const int gc  = strip * OUTC + lane - 4;          // column this lane owns
    const int gcc = min(max(gc, 0), WW - 1);          // clamped (safe addresses)
    const bool out_lane = (lane >= 4) && (lane < 4 + OUTC) && (gc < WW);
    const size_t plane = (size_t)HH * WW;
    const float* __restrict__ dispn  = disp  + (size_t)n * plane;
    const float* __restrict__ leftn  = left  + (size_t)n * CC * plane;
    const float* __restrict__ rightn = right + (size_t)n * CC * plane;

    // hoisted bpermute byte-addresses for the symmetric 3x3 window tree
    const int a_m1 = ((lane + 63) & 63) << 2;
    const int a_p1 = ((lane +  1) & 63) << 2;
    const int a_m3 = ((lane + 61) & 63) << 2;
    const int a_p3 = ((lane +  3) & 63) << 2;

    // vertical rolling ring (h-boxed rows, delay 8) — registers
    float4 rg1 = make_float4(0.f,0.f,0.f,0.f);
    float4 rg2=rg1, rg3=rg1, rg4=rg1, rg5=rg1, rg6=rg1, rg7=rg1, rg8=rg1;
    // center-row pixel chain (delay 4): left c0..c2, warped-right c0..c2
    float p1l0=0,p1l1=0,p1l2=0,p1r0=0,p1r1=0,p1r2=0;
    float p2l0=0,p2l1=0,p2l2=0,p2r0=0,p2r1=0,p2r2=0;
    float p3l0=0,p3l1=0,p3l2=0,p3r0=0,p3r1=0,p3r2=0;
    float p4l0=0,p4l1=0,p4l2=0,p4r0=0,p4r1=0,p4r2=0;

    const int r0 = h0 - 4;

    // ---- prologue: rows r0 and r0+1 ----
    int rcl = min(max(r0, 0), HH - 1);
    size_t ro = (size_t)rcl * WW + gcc;
    float dA  = dispn[ro];
    float al0 = leftn[ro], al1 = leftn[plane + ro], al2 = leftn[2*plane + ro];
    rcl = min(max(r0 + 1, 0), HH - 1);
    ro  = (size_t)rcl * WW + gcc;
    float dB  = dispn[ro];
    float bl0 = leftn[ro], bl1 = leftn[plane + ro], bl2 = leftn[2*plane + ro];

    float aw0, aw1, ag00, ag01, ag10, ag11, ag20, ag21;
    {
        float ix  = (float)gc - dA;
        float x0f = floorf(ix), wx = ix - x0f;
        int x0i = (int)x0f, x1i = x0i + 1;
        float v0 = (x0i >= 0 && x0i < WW) ? 1.f : 0.f;
        float v1 = (x1i >= 0 && x1i < WW) ? 1.f : 0.f;
        int i0 = min(max(x0i, 0), WW - 1), i1 = min(max(x1i, 0), WW - 1);
        aw0 = v0 * (1.f - wx); aw1 = v1 * wx;
        size_t rb = (size_t)min(max(r0, 0), HH - 1) * WW;
        ag00 = rightn[rb + i0];           ag01 = rightn[rb + i1];
        ag10 = rightn[plane + rb + i0];   ag11 = rightn[plane + rb + i1];
        ag20 = rightn[2*plane + rb + i0]; ag21 = rightn[2*plane + rb + i1];
    }

    float4 vsum = make_float4(0.f,0.f,0.f,0.f);
    float acc = 0.f;

    for (int iter = 0; iter < NITER; ++iter) {
        const int r = r0 + iter;

        // (1) issue loads for row r+2 (consumed next iter)
        int rcl2 = min(max(r + 2, 0), HH - 1);
        size_t ro2 = (size_t)rcl2 * WW + gcc;
        float dC  = dispn[ro2];
        float cl0 = leftn[ro2], cl1 = leftn[plane + ro2], cl2 = leftn[2*plane + ro2];

        // (2) issue gathers for row r+1 using dB (loaded last iter)
        float bw0, bw1, bg00, bg01, bg10, bg11, bg20, bg21;
        {
            float ix  = (float)gc - dB;
            float x0f = floorf(ix), wx = ix - x0f;
            int x0i = (int)x0f, x1i = x0i + 1;
            float v0 = (x0i >= 0 && x0i < WW) ? 1.f : 0.f;
            float v1 = (x1i >= 0 && x1i < WW) ? 1.f : 0.f;
            int i0 = min(max(x0i, 0), WW - 1), i1 = min(max(x1i, 0), WW - 1);
            bw0 = v0 * (1.f - wx); bw1 = v1 * wx;
            size_t rb = (size_t)min(max(r + 1, 0), HH - 1) * WW;
            bg00 = rightn[rb + i0];           bg01 = rightn[rb + i1];
            bg10 = rightn[plane + rb + i0];   bg11 = rightn[plane + rb + i1];
            bg20 = rightn[2*plane + rb + i0]; bg21 = rightn[2*plane + rb + i1];
        }

        // (3) combine raw channel sums for row r (gathers issued last iter)
        float rca = ag00*aw0 + ag01*aw1;
        float rcb = ag10*aw0 + ag11*aw1;
        float rcc = ag20*aw0 + ag21*aw1;
        bool valr = (r >= 0) && (r < HH) && (gc >= 0) && (gc < WW);
        float rx = al0 + al1 + al2;
        float ry = al0*al0 + al1*al1 + al2*al2;
        float rz = rca + rcb + rcc;
        float rw = rca*rca + rcb*rcb + rcc*rcc;
        rx = valr ? rx : 0.f;  ry = valr ? ry : 0.f;
        rz = valr ? rz : 0.f;  rw = valr ? rw : 0.f;

        // (4) horizontal 9-sum via symmetric 3x3 tree: 4 bpermutes/var, depth 2
        float sx = bperm(a_m1, rx) + rx + bperm(a_p1, rx);
        float sy = bperm(a_m1, ry) + ry + bperm(a_p1, ry);
        float sz = bperm(a_m1, rz) + rz + bperm(a_p1, rz);
        float sw = bperm(a_m1, rw) + rw + bperm(a_p1, rw);
        float hx = bperm(a_m3, sx) + sx + bperm(a_p3, sx);
        float hy = bperm(a_m3, sy) + sy + bperm(a_p3, sy);
        float hz = bperm(a_m3, sz) + sz + bperm(a_p3, sz);
        float hw = bperm(a_m3, sw) + sw + bperm(a_p3, sw);

        // (5) vertical rolling add
        vsum.x += hx; vsum.y += hy; vsum.z += hz; vsum.w += hw;

        // (6) output row h = r-4
        if (iter >= 8) {
            float ml   = vsum.x * (1.f / 81.f);
            float msl  = vsum.y * (1.f / 81.f);
            float stdl = (msl - ml * ml) * (81.f / 80.f);
            float invl = __builtin_amdgcn_rcpf(stdl + EPSL);
            float mr   = vsum.z * (1.f / 81.f);
            float msr  = vsum.w * (1.f / 81.f);
            float stdr = (msr - mr * mr) * (81.f / 80.f);
            float invr = __builtin_amdgcn_rcpf(stdr + EPSL);
            if (out_lane) {
                float av, bv;
                av = (p4l0 - ml) * invl; bv = (p4r0 - mr) * invr;
                acc += fabsf((av - bv) * stdl);
                av = (p4l1 - ml) * invl; bv = (p4r1 - mr) * invr;
                acc += fabsf((av - bv) * stdl);
                av = (p4l2 - ml) * invl; bv = (p4r2 - mr) * invr;
                acc += fabsf((av - bv) * stdl);
            }
            // (7) subtract h-boxed row pushed 8 iters ago
            vsum.x -= rg8.x; vsum.y -= rg8.y; vsum.z -= rg8.z; vsum.w -= rg8.w;
        }

        // (8) shift rings
        rg8 = rg7; rg7 = rg6; rg6 = rg5; rg5 = rg4; rg4 = rg3; rg3 = rg2; rg2 = rg1;
        rg1 = make_float4(hx, hy, hz, hw);
        p4l0=p3l0; p4l1=p3l1; p4l2=p3l2; p4r0=p3r0; p4r1=p3r1; p4r2=p3r2;
        p3l0=p2l0; p3l1=p2l1; p3l2=p2l2; p3r0=p2r0; p3r1=p2r1; p3r2=p2r2;
        p2l0=p1l0; p2l1=p1l1; p2l2=p1l2; p2r0=p1r0; p2r1=p1r1; p2r2=p1r2;
        p1l0=al0;  p1l1=al1;  p1l2=al2;  p1r0=rca;  p1r1=rcb;  p1r2=rcc;

        // (9) rotate packets: B -> A (row r+1 becomes current), C -> B
        al0=bl0; al1=bl1; al2=bl2;
        aw0=bw0; aw1=bw1;
        ag00=bg00; ag01=bg01; ag10=bg10; ag11=bg11; ag20=bg20; ag21=bg21;
        dB=dC; bl0=cl0; bl1=cl1; bl2=cl2;
    }

    // ---- reduction: wave shuffle -> LDS (4 slots) -> atomic ----
#pragma unroll
    for (int off = 32; off > 0; off >>= 1)
        acc += __shfl_down(acc, off, 64);
    __shared__ float red[4];
    if (lane == 0) red[t >> 6] = acc;
    __syncthreads();
    if (t == 0) {
        float s = red[0] + red[1] + red[2] + red[3];
        const float inv_count = 1.f / ((float)NB * CC * HH * WW);
        atomicAdd(out, s * inv_count);
    }
}

extern "C" void kernel_launch(void* const* d_in, const int* in_sizes, int n_in,
                              void* d_out, int out_size, void* d_ws, size_t ws_size,
                              hipStream_t stream) {
    const float* left  = (const float*)d_in[0];
    const float* right = (const float*)d_in[1];
    const float* disp  = (const float*)d_in[2];
    float* out = (float*)d_out;

    hipMemsetAsync(out, 0, sizeof(float) * out_size, stream);

    hipLaunchKernelGGL(fused_loss_kernel, dim3(NBLK), dim3(256), 0, stream,
                       left, right, disp, out);
}